// Round 1
// baseline (1181.798 us; speedup 1.0000x reference)
//
#include <hip/hip_runtime.h>
#include <hip/hip_bf16.h>

#define TOKENS 2048
#define FDIM 512
#define HDIM 2048
#define NEXP 8
#define PI_F 3.14159265358979323846f

// ---------------- ws layout ----------------
// counts: int[8]      @ 0
// offs:   int[8]      @ 64
// idx:    int[2048]   @ 128
// perm:   int[2048]   @ 8320
// hr:     bf16[2048*2048] @ 32768
// hi:     bf16[2048*2048] @ 32768 + 8388608
// total ~16.8 MB

__device__ __forceinline__ float bf2f(unsigned short u) {
  return __uint_as_float(((unsigned int)u) << 16);
}

__global__ __launch_bounds__(256) void route_kernel(
    const float* __restrict__ xr, const float* __restrict__ xi,
    int* __restrict__ idx, int* __restrict__ counts)
{
  int t = blockIdx.x;
  const float* r  = xr + (size_t)t * FDIM;
  const float* im = xi + (size_t)t * FDIM;
  int tid = threadIdx.x;
  float sc = 0.f, ss = 0.f;
  for (int f = tid; f < FDIM; f += 256) {
    float a = r[f], b = im[f];
    float h2 = a * a + b * b;
    if (h2 > 0.f) {
      float h = sqrtf(h2);
      sc += a / h;
      ss += b / h;
    } else {
      sc += 1.f;   // atan2(0,0)=0 -> cos=1, sin=0
    }
  }
  #pragma unroll
  for (int off = 32; off > 0; off >>= 1) {
    sc += __shfl_down(sc, off);
    ss += __shfl_down(ss, off);
  }
  __shared__ float red[8];
  int wave = tid >> 6;
  if ((tid & 63) == 0) { red[wave * 2] = sc; red[wave * 2 + 1] = ss; }
  __syncthreads();
  if (tid == 0) {
    float c = red[0] + red[2] + red[4] + red[6];
    float s = red[1] + red[3] + red[5] + red[7];
    float phase = atan2f(s, c);
    float norm = (phase + PI_F) / (2.f * PI_F);
    int e = (int)floorf(norm * (float)NEXP);
    e = min(max(e, 0), NEXP - 1);
    idx[t] = e;
    atomicAdd(&counts[e], 1);
  }
}

__global__ __launch_bounds__(256) void scatter_kernel(
    const int* __restrict__ idx, const int* __restrict__ counts,
    int* __restrict__ offs, int* __restrict__ perm)
{
  __shared__ int soffs[NEXP];
  __shared__ int scur[NEXP];
  int tid = threadIdx.x;
  if (tid == 0) {
    int acc = 0;
    for (int e = 0; e < NEXP; ++e) { soffs[e] = acc; offs[e] = acc; acc += counts[e]; }
  }
  if (tid < NEXP) scur[tid] = 0;
  __syncthreads();
  for (int t = tid; t < TOKENS; t += 256) {
    int e = idx[t];
    int pos = soffs[e] + atomicAdd(&scur[e], 1);
    perm[pos] = t;
  }
}

// ---- layer 1: [cnt x 512] @ [512 x 2048] complex, + bias + ModReLU -> bf16 h ----
__global__ __launch_bounds__(256) void gemm1_kernel(
    const float* __restrict__ xr, const float* __restrict__ xi,
    const float* __restrict__ Wr1, const float* __restrict__ Wi1,
    const float* __restrict__ br1, const float* __restrict__ bi1,
    const float* __restrict__ mb,
    const int* __restrict__ counts, const int* __restrict__ offs,
    const int* __restrict__ perm,
    __hip_bfloat16* __restrict__ hr_out, __hip_bfloat16* __restrict__ hi_out)
{
  int e = blockIdx.z;
  int cnt = counts[e];
  int row0 = blockIdx.y * 64;
  if (row0 >= cnt) return;
  int base = offs[e];
  int n0 = blockIdx.x * 64;

  __shared__ float xsr[64][17], xsi[64][17];
  __shared__ float wsr[16][64], wsi[16][64];

  int tid = threadIdx.x;
  int tx = tid & 15, ty = tid >> 4;

  // x staging: this thread always loads k = tid&15 for rows mrow+16*i
  int kk = tid & 15;
  int mrow = tid >> 4;
  int toks[4];
  #pragma unroll
  for (int i = 0; i < 4; ++i) {
    int row = row0 + mrow + 16 * i;
    int rc = row < cnt ? row : cnt - 1;
    toks[i] = perm[base + rc];
  }
  int wk = tid >> 6;   // 0..3
  int wn = tid & 63;
  const float* Wr = Wr1 + (size_t)e * FDIM * HDIM;
  const float* Wi = Wi1 + (size_t)e * FDIM * HDIM;

  float accr[4][4] = {}, acci[4][4] = {};

  for (int k0 = 0; k0 < FDIM; k0 += 16) {
    #pragma unroll
    for (int i = 0; i < 4; ++i) {
      xsr[mrow + 16 * i][kk] = xr[(size_t)toks[i] * FDIM + k0 + kk];
      xsi[mrow + 16 * i][kk] = xi[(size_t)toks[i] * FDIM + k0 + kk];
    }
    #pragma unroll
    for (int i = 0; i < 4; ++i) {
      wsr[wk + 4 * i][wn] = Wr[(size_t)(k0 + wk + 4 * i) * HDIM + n0 + wn];
      wsi[wk + 4 * i][wn] = Wi[(size_t)(k0 + wk + 4 * i) * HDIM + n0 + wn];
    }
    __syncthreads();
    #pragma unroll
    for (int k = 0; k < 16; ++k) {
      float ar[4], ai[4];
      #pragma unroll
      for (int j = 0; j < 4; ++j) {
        ar[j] = xsr[ty * 4 + j][k];
        ai[j] = xsi[ty * 4 + j][k];
      }
      float4 wr4 = *(const float4*)&wsr[k][tx * 4];
      float4 wi4 = *(const float4*)&wsi[k][tx * 4];
      float wrv[4] = {wr4.x, wr4.y, wr4.z, wr4.w};
      float wiv[4] = {wi4.x, wi4.y, wi4.z, wi4.w};
      #pragma unroll
      for (int j = 0; j < 4; ++j)
        #pragma unroll
        for (int n = 0; n < 4; ++n) {
          accr[j][n] += ar[j] * wrv[n] - ai[j] * wiv[n];
          acci[j][n] += ar[j] * wiv[n] + ai[j] * wrv[n];
        }
    }
    __syncthreads();
  }

  #pragma unroll
  for (int j = 0; j < 4; ++j) {
    int row = row0 + ty * 4 + j;
    if (row >= cnt) continue;
    size_t prow = (size_t)(base + row) * HDIM;
    #pragma unroll
    for (int n = 0; n < 4; ++n) {
      int col = n0 + tx * 4 + n;
      float hr = accr[j][n] + br1[e * HDIM + col];
      float hi = acci[j][n] + bi1[e * HDIM + col];
      float amp = sqrtf(hr * hr + hi * hi + 1e-10f);
      float s = fmaxf(amp + mb[e * HDIM + col], 0.f) / (amp + 1e-10f);
      hr *= s; hi *= s;
      hr_out[prow + col] = __float2bfloat16(hr);
      hi_out[prow + col] = __float2bfloat16(hi);
    }
  }
}

// ---- layer 2: [cnt x 2048] @ [2048 x 512] complex, + bias -> out (scatter by perm) ----
__global__ __launch_bounds__(256) void gemm2_kernel(
    const __hip_bfloat16* __restrict__ hr_in, const __hip_bfloat16* __restrict__ hi_in,
    const float* __restrict__ Wr2, const float* __restrict__ Wi2,
    const float* __restrict__ br2, const float* __restrict__ bi2,
    const int* __restrict__ counts, const int* __restrict__ offs,
    const int* __restrict__ perm,
    float* __restrict__ outr, float* __restrict__ outi)
{
  int e = blockIdx.z;
  int cnt = counts[e];
  int row0 = blockIdx.y * 32;
  if (row0 >= cnt) return;
  int base = offs[e];
  int n0 = blockIdx.x * 64;

  __shared__ float asr[32][17], asi[32][17];
  __shared__ float wsr[16][64], wsi[16][64];

  int tid = threadIdx.x;
  int tx = tid & 15, ty = tid >> 4;

  // A staging: ushort2 per plane: m = tid>>3 (0..31), k2 = (tid&7)*2
  int am = tid >> 3;
  int ak = (tid & 7) * 2;
  int arow = row0 + am;
  size_t aoff = (size_t)(base + (arow < cnt ? arow : cnt - 1)) * HDIM;
  const unsigned short* hr_u = (const unsigned short*)hr_in;
  const unsigned short* hi_u = (const unsigned short*)hi_in;

  int wk = tid >> 6;
  int wn = tid & 63;
  const float* Wr = Wr2 + (size_t)e * HDIM * FDIM;
  const float* Wi = Wi2 + (size_t)e * HDIM * FDIM;

  float accr[2][4] = {}, acci[2][4] = {};

  for (int k0 = 0; k0 < HDIM; k0 += 16) {
    ushort2 ur = *(const ushort2*)(hr_u + aoff + k0 + ak);
    ushort2 ui = *(const ushort2*)(hi_u + aoff + k0 + ak);
    asr[am][ak] = bf2f(ur.x); asr[am][ak + 1] = bf2f(ur.y);
    asi[am][ak] = bf2f(ui.x); asi[am][ak + 1] = bf2f(ui.y);
    #pragma unroll
    for (int i = 0; i < 4; ++i) {
      wsr[wk + 4 * i][wn] = Wr[(size_t)(k0 + wk + 4 * i) * FDIM + n0 + wn];
      wsi[wk + 4 * i][wn] = Wi[(size_t)(k0 + wk + 4 * i) * FDIM + n0 + wn];
    }
    __syncthreads();
    #pragma unroll
    for (int k = 0; k < 16; ++k) {
      float ar[2], ai[2];
      ar[0] = asr[ty * 2][k];     ar[1] = asr[ty * 2 + 1][k];
      ai[0] = asi[ty * 2][k];     ai[1] = asi[ty * 2 + 1][k];
      float4 wr4 = *(const float4*)&wsr[k][tx * 4];
      float4 wi4 = *(const float4*)&wsi[k][tx * 4];
      float wrv[4] = {wr4.x, wr4.y, wr4.z, wr4.w};
      float wiv[4] = {wi4.x, wi4.y, wi4.z, wi4.w};
      #pragma unroll
      for (int j = 0; j < 2; ++j)
        #pragma unroll
        for (int n = 0; n < 4; ++n) {
          accr[j][n] += ar[j] * wrv[n] - ai[j] * wiv[n];
          acci[j][n] += ar[j] * wiv[n] + ai[j] * wrv[n];
        }
    }
    __syncthreads();
  }

  #pragma unroll
  for (int j = 0; j < 2; ++j) {
    int row = row0 + ty * 2 + j;
    if (row >= cnt) continue;
    int tok = perm[base + row];
    #pragma unroll
    for (int n = 0; n < 4; ++n) {
      int col = n0 + tx * 4 + n;
      outr[(size_t)tok * FDIM + col] = accr[j][n] + br2[e * FDIM + col];
      outi[(size_t)tok * FDIM + col] = acci[j][n] + bi2[e * FDIM + col];
    }
  }
}

extern "C" void kernel_launch(void* const* d_in, const int* in_sizes, int n_in,
                              void* d_out, int out_size, void* d_ws, size_t ws_size,
                              hipStream_t stream)
{
  const float* xr  = (const float*)d_in[0];
  const float* xi  = (const float*)d_in[1];
  const float* Wr1 = (const float*)d_in[2];
  const float* Wi1 = (const float*)d_in[3];
  const float* br1 = (const float*)d_in[4];
  const float* bi1 = (const float*)d_in[5];
  const float* mb  = (const float*)d_in[6];
  const float* Wr2 = (const float*)d_in[7];
  const float* Wi2 = (const float*)d_in[8];
  const float* br2 = (const float*)d_in[9];
  const float* bi2 = (const float*)d_in[10];
  float* out = (float*)d_out;

  char* ws = (char*)d_ws;
  int* counts = (int*)(ws + 0);
  int* offs   = (int*)(ws + 64);
  int* idx    = (int*)(ws + 128);
  int* perm   = (int*)(ws + 8320);
  __hip_bfloat16* hr = (__hip_bfloat16*)(ws + 32768);
  __hip_bfloat16* hi = (__hip_bfloat16*)(ws + 32768 + (size_t)TOKENS * HDIM * 2);

  hipMemsetAsync(counts, 0, 64, stream);
  route_kernel<<<TOKENS, 256, 0, stream>>>(xr, xi, idx, counts);
  scatter_kernel<<<1, 256, 0, stream>>>(idx, counts, offs, perm);
  gemm1_kernel<<<dim3(HDIM / 64, TOKENS / 64, NEXP), 256, 0, stream>>>(
      xr, xi, Wr1, Wi1, br1, bi1, mb, counts, offs, perm, hr, hi);
  gemm2_kernel<<<dim3(FDIM / 64, TOKENS / 32, NEXP), 256, 0, stream>>>(
      hr, hi, Wr2, Wi2, br2, bi2, counts, offs, perm,
      out, out + (size_t)TOKENS * FDIM);
}

// Round 2
// 262.318 us; speedup vs baseline: 4.5052x; 4.5052x over previous
//
#include <hip/hip_runtime.h>
#include <hip/hip_bf16.h>

#define TOKENS 2048
#define FDIM 512
#define HDIM 2048
#define NEXP 8
#define PI_F 3.14159265358979323846f

typedef __attribute__((ext_vector_type(8))) short bf16x8;
typedef __attribute__((ext_vector_type(4))) float f32x4;

__device__ __forceinline__ unsigned short f2bf(float f) {
  unsigned int u = __float_as_uint(f);
  unsigned int r = (u + 0x7fffu + ((u >> 16) & 1u)) >> 16;
  return (unsigned short)r;
}
__device__ __forceinline__ float bf2f(unsigned short u) {
  return __uint_as_float(((unsigned int)u) << 16);
}

// ---------------- routing ----------------
__global__ __launch_bounds__(256) void route_kernel(
    const float* __restrict__ xr, const float* __restrict__ xi,
    int* __restrict__ idx, int* __restrict__ counts)
{
  int t = blockIdx.x;
  const float* r  = xr + (size_t)t * FDIM;
  const float* im = xi + (size_t)t * FDIM;
  int tid = threadIdx.x;
  float sc = 0.f, ss = 0.f;
  for (int f = tid; f < FDIM; f += 256) {
    float a = r[f], b = im[f];
    float h2 = a * a + b * b;
    if (h2 > 0.f) {
      float h = sqrtf(h2);
      sc += a / h;
      ss += b / h;
    } else {
      sc += 1.f;
    }
  }
  #pragma unroll
  for (int off = 32; off > 0; off >>= 1) {
    sc += __shfl_down(sc, off);
    ss += __shfl_down(ss, off);
  }
  __shared__ float red[8];
  int wave = tid >> 6;
  if ((tid & 63) == 0) { red[wave * 2] = sc; red[wave * 2 + 1] = ss; }
  __syncthreads();
  if (tid == 0) {
    float c = red[0] + red[2] + red[4] + red[6];
    float s = red[1] + red[3] + red[5] + red[7];
    float phase = atan2f(s, c);
    float norm = (phase + PI_F) / (2.f * PI_F);
    int e = (int)floorf(norm * (float)NEXP);
    e = min(max(e, 0), NEXP - 1);
    idx[t] = e;
    atomicAdd(&counts[e], 1);
  }
}

__global__ __launch_bounds__(256) void scatter_kernel(
    const int* __restrict__ idx, const int* __restrict__ counts,
    int* __restrict__ offs, int* __restrict__ perm)
{
  __shared__ int soffs[NEXP];
  __shared__ int scur[NEXP];
  int tid = threadIdx.x;
  if (tid == 0) {
    int acc = 0;
    for (int e = 0; e < NEXP; ++e) { soffs[e] = acc; offs[e] = acc; acc += counts[e]; }
  }
  if (tid < NEXP) scur[tid] = 0;
  __syncthreads();
  for (int t = tid; t < TOKENS; t += 256) {
    int e = idx[t];
    int pos = soffs[e] + atomicAdd(&scur[e], 1);
    perm[pos] = t;
  }
}

// ---------------- MFMA path: packing ----------------
// A1[i][k], k=2c -> xr, 2c+1 -> xi  (bf16, [2048][1024])
__global__ __launch_bounds__(256) void pack_x_kernel(
    const float* __restrict__ xr, const float* __restrict__ xi,
    const int* __restrict__ perm, short* __restrict__ A1)
{
  int gid = blockIdx.x * 256 + threadIdx.x;   // 2048 * 128
  int i = gid >> 7;
  int cq = (gid & 127) * 4;
  int tok = perm[i];
  float4 r = *(const float4*)(xr + (size_t)tok * FDIM + cq);
  float4 m = *(const float4*)(xi + (size_t)tok * FDIM + cq);
  unsigned short o[8] = { f2bf(r.x), f2bf(m.x), f2bf(r.y), f2bf(m.y),
                          f2bf(r.z), f2bf(m.z), f2bf(r.w), f2bf(m.w) };
  *(int4*)(A1 + (size_t)i * 1024 + 2 * cq) = *(const int4*)o;
}

// src W[e][R][C] fp32 (C contiguous) -> dst[e][2C][2R] bf16, N-major:
//   dst[2c][2r] = Wr, dst[2c][2r+1] = -Wi, dst[2c+1][2r] = Wi, dst[2c+1][2r+1] = Wr
// dst viewed as uint: [e][2C][R] uints (low short = even k)
template<int R, int C>
__global__ __launch_bounds__(256) void pack_w_kernel(
    const float* __restrict__ Wr, const float* __restrict__ Wi,
    unsigned int* __restrict__ dst)
{
  int e = blockIdx.z;
  int r0 = blockIdx.y * 32, c0 = blockIdx.x * 32;
  __shared__ float tr[32][33], ti[32][33];
  int tid = threadIdx.x;
  int rr = tid >> 5, cc = tid & 31;
  const float* wr = Wr + ((size_t)e * R + r0) * C + c0;
  const float* wi = Wi + ((size_t)e * R + r0) * C + c0;
  #pragma unroll
  for (int s = 0; s < 4; ++s) {
    tr[rr + s * 8][cc] = wr[(size_t)(rr + s * 8) * C + cc];
    ti[rr + s * 8][cc] = wi[(size_t)(rr + s * 8) * C + cc];
  }
  __syncthreads();
  #pragma unroll
  for (int s = 0; s < 4; ++s) {
    int cl = rr + s * 8, rl = cc;
    float vr = tr[rl][cl], vi = ti[rl][cl];
    size_t b = ((size_t)e * 2 * C + 2 * (size_t)(c0 + cl)) * R + (r0 + rl);
    dst[b]     = (unsigned int)f2bf(vr) | ((unsigned int)f2bf(-vi) << 16);
    dst[b + R] = (unsigned int)f2bf(vi) | ((unsigned int)f2bf(vr) << 16);
  }
}

// ---------------- MFMA grouped GEMM ----------------
// A [2048][K] bf16 row-major, Bp [E][N][K] bf16 N-major.
// L1: epilogue = +bias, ModReLU (pair via shfl_xor 1), write bf16 A2[2048][N].
// L2: epilogue = +bias, scatter f32 rows to out via perm.
template<int BM, int MF, int NF, int K, int N, bool L1>
__global__ __launch_bounds__(256) void gemm_mfma_kernel(
    const short* __restrict__ A, const short* __restrict__ Bp,
    const int* __restrict__ counts, const int* __restrict__ offs,
    const int* __restrict__ perm,
    const float* __restrict__ bre, const float* __restrict__ bim,
    const float* __restrict__ mb,
    short* __restrict__ OutBf, float* __restrict__ OutF)
{
  constexpr int BN = 2 * NF * 16;
  int e = blockIdx.z;
  int cnt = counts[e];
  int row0 = blockIdx.y * BM;
  if (row0 >= cnt) return;
  int base = offs[e];
  int n0 = blockIdx.x * BN;

  __shared__ __align__(16) short As[BM][40];
  __shared__ __align__(16) short Bs[BN][40];

  int tid = threadIdx.x;
  int lane = tid & 63;
  int w = tid >> 6, wm = w >> 1, wn = w & 1;
  int lr = lane & 15, lk = (lane >> 4) * 8;

  const short* Be = Bp + (size_t)e * N * K;

  int srow = tid >> 2, sseg = (tid & 3) * 8;
  const short* aptr[BM / 64];
  const short* bptr[BN / 64];
  #pragma unroll
  for (int it = 0; it < BM / 64; ++it) {
    int rc = min(row0 + it * 64 + srow, cnt - 1);
    aptr[it] = A + (size_t)(base + rc) * K + sseg;
  }
  #pragma unroll
  for (int it = 0; it < BN / 64; ++it)
    bptr[it] = Be + (size_t)(n0 + it * 64 + srow) * K + sseg;

  f32x4 acc[MF][NF];
  #pragma unroll
  for (int m = 0; m < MF; ++m)
    #pragma unroll
    for (int n = 0; n < NF; ++n) acc[m][n] = 0.f;

  for (int k0 = 0; k0 < K; k0 += 32) {
    #pragma unroll
    for (int it = 0; it < BM / 64; ++it) {
      int4 v = *(const int4*)(aptr[it] + k0);
      *(int4*)&As[it * 64 + srow][sseg] = v;
    }
    #pragma unroll
    for (int it = 0; it < BN / 64; ++it) {
      int4 v = *(const int4*)(bptr[it] + k0);
      *(int4*)&Bs[it * 64 + srow][sseg] = v;
    }
    __syncthreads();
    bf16x8 af[MF], bv[NF];
    #pragma unroll
    for (int m = 0; m < MF; ++m)
      af[m] = *(const bf16x8*)&As[wm * MF * 16 + m * 16 + lr][lk];
    #pragma unroll
    for (int n = 0; n < NF; ++n)
      bv[n] = *(const bf16x8*)&Bs[wn * NF * 16 + n * 16 + lr][lk];
    #pragma unroll
    for (int m = 0; m < MF; ++m)
      #pragma unroll
      for (int n = 0; n < NF; ++n)
        acc[m][n] = __builtin_amdgcn_mfma_f32_16x16x32_bf16(af[m], bv[n], acc[m][n], 0, 0, 0);
    __syncthreads();
  }

  #pragma unroll
  for (int m = 0; m < MF; ++m) {
    #pragma unroll
    for (int q = 0; q < 4; ++q) {
      int row = row0 + wm * MF * 16 + m * 16 + (lane >> 4) * 4 + q;
      bool valid = row < cnt;
      int tok = 0;
      if (!L1) tok = perm[base + min(row, cnt - 1)];
      #pragma unroll
      for (int n = 0; n < NF; ++n) {
        int col = n0 + wn * NF * 16 + n * 16 + lr;
        int c = col >> 1;
        bool re = (col & 1) == 0;
        float v = acc[m][n][q] + (re ? bre[e * (N / 2) + c] : bim[e * (N / 2) + c]);
        if (L1) {
          float o = __shfl_xor(v, 1);
          float hr = re ? v : o, hi = re ? o : v;
          float amp = sqrtf(hr * hr + hi * hi + 1e-10f);
          float s = fmaxf(amp + mb[e * (N / 2) + c], 0.f) / (amp + 1e-10f);
          v *= s;
          if (valid) OutBf[(size_t)(base + row) * N + col] = (short)f2bf(v);
        } else {
          if (valid) OutF[(re ? 0 : (size_t)TOKENS * FDIM) + (size_t)tok * FDIM + c] = v;
        }
      }
    }
  }
}

// ---------------- fallback fp32 path (round-1, verified) ----------------
__global__ __launch_bounds__(256) void gemm1_kernel(
    const float* __restrict__ xr, const float* __restrict__ xi,
    const float* __restrict__ Wr1, const float* __restrict__ Wi1,
    const float* __restrict__ br1, const float* __restrict__ bi1,
    const float* __restrict__ mb,
    const int* __restrict__ counts, const int* __restrict__ offs,
    const int* __restrict__ perm,
    __hip_bfloat16* __restrict__ hr_out, __hip_bfloat16* __restrict__ hi_out)
{
  int e = blockIdx.z;
  int cnt = counts[e];
  int row0 = blockIdx.y * 64;
  if (row0 >= cnt) return;
  int base = offs[e];
  int n0 = blockIdx.x * 64;
  __shared__ float xsr[64][17], xsi[64][17];
  __shared__ float wsr[16][64], wsi[16][64];
  int tid = threadIdx.x;
  int tx = tid & 15, ty = tid >> 4;
  int kk = tid & 15;
  int mrow = tid >> 4;
  int toks[4];
  #pragma unroll
  for (int i = 0; i < 4; ++i) {
    int row = row0 + mrow + 16 * i;
    int rc = row < cnt ? row : cnt - 1;
    toks[i] = perm[base + rc];
  }
  int wk = tid >> 6;
  int wn = tid & 63;
  const float* Wr = Wr1 + (size_t)e * FDIM * HDIM;
  const float* Wi = Wi1 + (size_t)e * FDIM * HDIM;
  float accr[4][4] = {}, acci[4][4] = {};
  for (int k0 = 0; k0 < FDIM; k0 += 16) {
    #pragma unroll
    for (int i = 0; i < 4; ++i) {
      xsr[mrow + 16 * i][kk] = xr[(size_t)toks[i] * FDIM + k0 + kk];
      xsi[mrow + 16 * i][kk] = xi[(size_t)toks[i] * FDIM + k0 + kk];
    }
    #pragma unroll
    for (int i = 0; i < 4; ++i) {
      wsr[wk + 4 * i][wn] = Wr[(size_t)(k0 + wk + 4 * i) * HDIM + n0 + wn];
      wsi[wk + 4 * i][wn] = Wi[(size_t)(k0 + wk + 4 * i) * HDIM + n0 + wn];
    }
    __syncthreads();
    #pragma unroll
    for (int k = 0; k < 16; ++k) {
      float ar[4], ai[4];
      #pragma unroll
      for (int j = 0; j < 4; ++j) { ar[j] = xsr[ty * 4 + j][k]; ai[j] = xsi[ty * 4 + j][k]; }
      float4 wr4 = *(const float4*)&wsr[k][tx * 4];
      float4 wi4 = *(const float4*)&wsi[k][tx * 4];
      float wrv[4] = {wr4.x, wr4.y, wr4.z, wr4.w};
      float wiv[4] = {wi4.x, wi4.y, wi4.z, wi4.w};
      #pragma unroll
      for (int j = 0; j < 4; ++j)
        #pragma unroll
        for (int n = 0; n < 4; ++n) {
          accr[j][n] += ar[j] * wrv[n] - ai[j] * wiv[n];
          acci[j][n] += ar[j] * wiv[n] + ai[j] * wrv[n];
        }
    }
    __syncthreads();
  }
  #pragma unroll
  for (int j = 0; j < 4; ++j) {
    int row = row0 + ty * 4 + j;
    if (row >= cnt) continue;
    size_t prow = (size_t)(base + row) * HDIM;
    #pragma unroll
    for (int n = 0; n < 4; ++n) {
      int col = n0 + tx * 4 + n;
      float hr = accr[j][n] + br1[e * HDIM + col];
      float hi = acci[j][n] + bi1[e * HDIM + col];
      float amp = sqrtf(hr * hr + hi * hi + 1e-10f);
      float s = fmaxf(amp + mb[e * HDIM + col], 0.f) / (amp + 1e-10f);
      hr_out[prow + col] = __float2bfloat16(hr * s);
      hi_out[prow + col] = __float2bfloat16(hi * s);
    }
  }
}

__global__ __launch_bounds__(256) void gemm2_kernel(
    const __hip_bfloat16* __restrict__ hr_in, const __hip_bfloat16* __restrict__ hi_in,
    const float* __restrict__ Wr2, const float* __restrict__ Wi2,
    const float* __restrict__ br2, const float* __restrict__ bi2,
    const int* __restrict__ counts, const int* __restrict__ offs,
    const int* __restrict__ perm,
    float* __restrict__ outr, float* __restrict__ outi)
{
  int e = blockIdx.z;
  int cnt = counts[e];
  int row0 = blockIdx.y * 32;
  if (row0 >= cnt) return;
  int base = offs[e];
  int n0 = blockIdx.x * 64;
  __shared__ float asr[32][17], asi[32][17];
  __shared__ float wsr[16][64], wsi[16][64];
  int tid = threadIdx.x;
  int tx = tid & 15, ty = tid >> 4;
  int am = tid >> 3;
  int ak = (tid & 7) * 2;
  int arow = row0 + am;
  size_t aoff = (size_t)(base + (arow < cnt ? arow : cnt - 1)) * HDIM;
  const unsigned short* hr_u = (const unsigned short*)hr_in;
  const unsigned short* hi_u = (const unsigned short*)hi_in;
  int wk = tid >> 6;
  int wn = tid & 63;
  const float* Wr = Wr2 + (size_t)e * HDIM * FDIM;
  const float* Wi = Wi2 + (size_t)e * HDIM * FDIM;
  float accr[2][4] = {}, acci[2][4] = {};
  for (int k0 = 0; k0 < HDIM; k0 += 16) {
    ushort2 ur = *(const ushort2*)(hr_u + aoff + k0 + ak);
    ushort2 ui = *(const ushort2*)(hi_u + aoff + k0 + ak);
    asr[am][ak] = bf2f(ur.x); asr[am][ak + 1] = bf2f(ur.y);
    asi[am][ak] = bf2f(ui.x); asi[am][ak + 1] = bf2f(ui.y);
    #pragma unroll
    for (int i = 0; i < 4; ++i) {
      wsr[wk + 4 * i][wn] = Wr[(size_t)(k0 + wk + 4 * i) * FDIM + n0 + wn];
      wsi[wk + 4 * i][wn] = Wi[(size_t)(k0 + wk + 4 * i) * FDIM + n0 + wn];
    }
    __syncthreads();
    #pragma unroll
    for (int k = 0; k < 16; ++k) {
      float ar[2], ai[2];
      ar[0] = asr[ty * 2][k];     ar[1] = asr[ty * 2 + 1][k];
      ai[0] = asi[ty * 2][k];     ai[1] = asi[ty * 2 + 1][k];
      float4 wr4 = *(const float4*)&wsr[k][tx * 4];
      float4 wi4 = *(const float4*)&wsi[k][tx * 4];
      float wrv[4] = {wr4.x, wr4.y, wr4.z, wr4.w};
      float wiv[4] = {wi4.x, wi4.y, wi4.z, wi4.w};
      #pragma unroll
      for (int j = 0; j < 2; ++j)
        #pragma unroll
        for (int n = 0; n < 4; ++n) {
          accr[j][n] += ar[j] * wrv[n] - ai[j] * wiv[n];
          acci[j][n] += ar[j] * wiv[n] + ai[j] * wrv[n];
        }
    }
    __syncthreads();
  }
  #pragma unroll
  for (int j = 0; j < 2; ++j) {
    int row = row0 + ty * 2 + j;
    if (row >= cnt) continue;
    int tok = perm[base + row];
    #pragma unroll
    for (int n = 0; n < 4; ++n) {
      int col = n0 + tx * 4 + n;
      outr[(size_t)tok * FDIM + col] = accr[j][n] + br2[e * FDIM + col];
      outi[(size_t)tok * FDIM + col] = acci[j][n] + bi2[e * FDIM + col];
    }
  }
}

extern "C" void kernel_launch(void* const* d_in, const int* in_sizes, int n_in,
                              void* d_out, int out_size, void* d_ws, size_t ws_size,
                              hipStream_t stream)
{
  const float* xr  = (const float*)d_in[0];
  const float* xi  = (const float*)d_in[1];
  const float* Wr1 = (const float*)d_in[2];
  const float* Wi1 = (const float*)d_in[3];
  const float* br1 = (const float*)d_in[4];
  const float* bi1 = (const float*)d_in[5];
  const float* mb  = (const float*)d_in[6];
  const float* Wr2 = (const float*)d_in[7];
  const float* Wi2 = (const float*)d_in[8];
  const float* br2 = (const float*)d_in[9];
  const float* bi2 = (const float*)d_in[10];
  float* out = (float*)d_out;

  char* ws = (char*)d_ws;
  int* counts = (int*)(ws + 0);
  int* offs   = (int*)(ws + 64);
  int* idx    = (int*)(ws + 128);
  int* perm   = (int*)(ws + 8320);

  // MFMA-path layout
  const size_t A1_OFF = 32768;
  const size_t A2_OFF = A1_OFF + (size_t)TOKENS * 1024 * 2;          // 4 MB
  const size_t B1_OFF = A2_OFF + (size_t)TOKENS * 4096 * 2;          // 16 MB
  const size_t B2_OFF = B1_OFF + (size_t)NEXP * 4096 * 1024 * 2;     // 64 MB
  const size_t NEED   = B2_OFF + (size_t)NEXP * 1024 * 4096 * 2;     // 64 MB

  hipMemsetAsync(counts, 0, 64, stream);
  route_kernel<<<TOKENS, 256, 0, stream>>>(xr, xi, idx, counts);
  scatter_kernel<<<1, 256, 0, stream>>>(idx, counts, offs, perm);

  if (ws_size >= NEED) {
    short* A1 = (short*)(ws + A1_OFF);
    short* A2 = (short*)(ws + A2_OFF);
    short* B1 = (short*)(ws + B1_OFF);
    short* B2 = (short*)(ws + B2_OFF);

    pack_x_kernel<<<TOKENS * 128 / 256, 256, 0, stream>>>(xr, xi, perm, A1);
    pack_w_kernel<512, 2048><<<dim3(2048 / 32, 512 / 32, NEXP), 256, 0, stream>>>(
        Wr1, Wi1, (unsigned int*)B1);
    pack_w_kernel<2048, 512><<<dim3(512 / 32, 2048 / 32, NEXP), 256, 0, stream>>>(
        Wr2, Wi2, (unsigned int*)B2);

    // layer1: [2048 x 1024] @ [4096 x 1024]^T-style -> A2 (bf16, ModReLU fused)
    gemm_mfma_kernel<128, 4, 4, 1024, 4096, true>
        <<<dim3(4096 / 128, TOKENS / 128, NEXP), 256, 0, stream>>>(
        A1, B1, counts, offs, perm, br1, bi1, mb, A2, nullptr);
    // layer2: [2048 x 4096] @ [1024 x 4096] -> out (f32, scatter)
    gemm_mfma_kernel<64, 2, 4, 4096, 1024, false>
        <<<dim3(1024 / 128, TOKENS / 64, NEXP), 256, 0, stream>>>(
        A2, B2, counts, offs, perm, br2, bi2, nullptr, nullptr, out);
  } else {
    __hip_bfloat16* hr = (__hip_bfloat16*)(ws + 32768);
    __hip_bfloat16* hi = (__hip_bfloat16*)(ws + 32768 + (size_t)TOKENS * HDIM * 2);
    gemm1_kernel<<<dim3(HDIM / 64, TOKENS / 64, NEXP), 256, 0, stream>>>(
        xr, xi, Wr1, Wi1, br1, bi1, mb, counts, offs, perm, hr, hi);
    gemm2_kernel<<<dim3(FDIM / 64, TOKENS / 32, NEXP), 256, 0, stream>>>(
        hr, hi, Wr2, Wi2, br2, bi2, counts, offs, perm,
        out, out + (size_t)TOKENS * FDIM);
  }
}

// Round 3
// 199.404 us; speedup vs baseline: 5.9266x; 1.3155x over previous
//
#include <hip/hip_runtime.h>
#include <hip/hip_bf16.h>

#define TOKENS 2048
#define FDIM 512
#define HDIM 2048
#define NEXP 8
#define PI_F 3.14159265358979323846f

typedef __attribute__((ext_vector_type(8))) short bf16x8;
typedef __attribute__((ext_vector_type(4))) float f32x4;

__device__ __forceinline__ unsigned short f2bf(float f) {
  unsigned int u = __float_as_uint(f);
  unsigned int r = (u + 0x7fffu + ((u >> 16) & 1u)) >> 16;
  return (unsigned short)r;
}

__device__ __forceinline__ void gload16(const void* g, void* l) {
  __builtin_amdgcn_global_load_lds(
      (const __attribute__((address_space(1))) unsigned int*)g,
      (__attribute__((address_space(3))) unsigned int*)l, 16, 0, 0);
}

// ---------------- routing ----------------
__global__ __launch_bounds__(256) void route_kernel(
    const float* __restrict__ xr, const float* __restrict__ xi,
    int* __restrict__ idx, int* __restrict__ counts)
{
  int t = blockIdx.x;
  const float* r  = xr + (size_t)t * FDIM;
  const float* im = xi + (size_t)t * FDIM;
  int tid = threadIdx.x;
  float sc = 0.f, ss = 0.f;
  for (int f = tid; f < FDIM; f += 256) {
    float a = r[f], b = im[f];
    float h2 = a * a + b * b;
    if (h2 > 0.f) {
      float h = sqrtf(h2);
      sc += a / h;
      ss += b / h;
    } else {
      sc += 1.f;
    }
  }
  #pragma unroll
  for (int off = 32; off > 0; off >>= 1) {
    sc += __shfl_down(sc, off);
    ss += __shfl_down(ss, off);
  }
  __shared__ float red[8];
  int wave = tid >> 6;
  if ((tid & 63) == 0) { red[wave * 2] = sc; red[wave * 2 + 1] = ss; }
  __syncthreads();
  if (tid == 0) {
    float c = red[0] + red[2] + red[4] + red[6];
    float s = red[1] + red[3] + red[5] + red[7];
    float phase = atan2f(s, c);
    float norm = (phase + PI_F) / (2.f * PI_F);
    int e = (int)floorf(norm * (float)NEXP);
    e = min(max(e, 0), NEXP - 1);
    idx[t] = e;
    atomicAdd(&counts[e], 1);
  }
}

__global__ __launch_bounds__(256) void scatter_kernel(
    const int* __restrict__ idx, const int* __restrict__ counts,
    int* __restrict__ offs, int* __restrict__ perm, int* __restrict__ rexp)
{
  __shared__ int soffs[NEXP];
  __shared__ int scur[NEXP];
  int tid = threadIdx.x;
  if (tid == 0) {
    int acc = 0;
    for (int e = 0; e < NEXP; ++e) { soffs[e] = acc; offs[e] = acc; acc += counts[e]; }
  }
  if (tid < NEXP) scur[tid] = 0;
  __syncthreads();
  for (int t = tid; t < TOKENS; t += 256) {
    int e = idx[t];
    int pos = soffs[e] + atomicAdd(&scur[e], 1);
    perm[pos] = t;
    rexp[pos] = e;
  }
}

// ---------------- packing ----------------
// A1[i][k], k=2c -> xr, 2c+1 -> xi  (bf16, [2048][1024]), rows permuted-compact
__global__ __launch_bounds__(256) void pack_x_kernel(
    const float* __restrict__ xr, const float* __restrict__ xi,
    const int* __restrict__ perm, short* __restrict__ A1)
{
  int gid = blockIdx.x * 256 + threadIdx.x;   // 2048 * 128
  int i = gid >> 7;
  int cq = (gid & 127) * 4;
  int tok = perm[i];
  float4 r = *(const float4*)(xr + (size_t)tok * FDIM + cq);
  float4 m = *(const float4*)(xi + (size_t)tok * FDIM + cq);
  unsigned short o[8] = { f2bf(r.x), f2bf(m.x), f2bf(r.y), f2bf(m.y),
                          f2bf(r.z), f2bf(m.z), f2bf(r.w), f2bf(m.w) };
  *(int4*)(A1 + (size_t)i * 1024 + 2 * cq) = *(const int4*)o;
}

// W[e][R][C] fp32 -> dst[e][2C][2R] bf16 N-major:
//   dst[2c][2r]=Wr, dst[2c][2r+1]=-Wi, dst[2c+1][2r]=Wi, dst[2c+1][2r+1]=Wr
template<int R, int C>
__global__ __launch_bounds__(256) void pack_w_kernel(
    const float* __restrict__ Wr, const float* __restrict__ Wi,
    unsigned int* __restrict__ dst)
{
  int e = blockIdx.z;
  int r0 = blockIdx.y * 32, c0 = blockIdx.x * 32;
  __shared__ float tr[32][33], ti[32][33];
  int tid = threadIdx.x;
  int rr = tid >> 5, cc = tid & 31;
  const float* wr = Wr + ((size_t)e * R + r0) * C + c0;
  const float* wi = Wi + ((size_t)e * R + r0) * C + c0;
  #pragma unroll
  for (int s = 0; s < 4; ++s) {
    tr[rr + s * 8][cc] = wr[(size_t)(rr + s * 8) * C + cc];
    ti[rr + s * 8][cc] = wi[(size_t)(rr + s * 8) * C + cc];
  }
  __syncthreads();
  #pragma unroll
  for (int s = 0; s < 4; ++s) {
    int cl = rr + s * 8, rl = cc;
    float vr = tr[rl][cl], vi = ti[rl][cl];
    size_t b = ((size_t)e * 2 * C + 2 * (size_t)(c0 + cl)) * R + (r0 + rl);
    dst[b]     = (unsigned int)f2bf(vr) | ((unsigned int)f2bf(-vi) << 16);
    dst[b + R] = (unsigned int)f2bf(vi) | ((unsigned int)f2bf(vr) << 16);
  }
}

// ---------------- MFMA grouped GEMM (BK=64, dbuf, gload_lds, XOR swizzle) ----
// A [2048][LDA] bf16 compact rows; Bp [E][NTOT][LDA] bf16 N-major.
// z = s*NEXP + e; K-chunk = [s*1024, s*1024+1024).
// IS_L1: epilogue bias+ModReLU -> bf16 OutBf. else: partial f32 -> OutP.
template<int BM, int MF, int NF, int LDA, int NTOT, bool IS_L1>
__global__ __launch_bounds__(256) void gemm_mfma2(
    const short* __restrict__ A, const short* __restrict__ Bp,
    const int* __restrict__ counts, const int* __restrict__ offs,
    const float* __restrict__ bre, const float* __restrict__ bim,
    const float* __restrict__ mb,
    short* __restrict__ OutBf, float* __restrict__ OutP)
{
  constexpr int BN = NF * 32;   // 128
  constexpr int KT = 16;        // 16 tiles x 64 = 1024 K-chunk
  int z = blockIdx.z;
  int e = z & 7, s = z >> 3;
  int cnt = counts[e];
  int row0 = blockIdx.y * BM;
  if (row0 >= cnt) return;
  int base = offs[e];
  int n0 = blockIdx.x * BN;
  int kbase = s * 1024;

  __shared__ __align__(16) short As[2][BM][64];
  __shared__ __align__(16) short Bs[2][BN][64];

  int tid = threadIdx.x;
  int lane = tid & 63;
  int w = tid >> 6, wm = w >> 1, wn = w & 1;
  int lr = lane & 15, g = lane >> 4;

  const short* Be = Bp + (size_t)e * NTOT * LDA;

  // staging sources: thread -> (row = b*32 + tid/8, lds slot = tid&7),
  // global slot pre-swizzled: slot ^ (row&7)   [rule #21 both-sides]
  int srow = tid >> 3, slot = tid & 7;
  const char* aptr[BM / 32];
  #pragma unroll
  for (int b = 0; b < BM / 32; ++b) {
    int row = b * 32 + srow;
    int rc = min(row0 + row, cnt - 1);
    aptr[b] = (const char*)(A + (size_t)(base + rc) * LDA + kbase)
              + ((slot ^ (row & 7)) * 16);
  }
  const char* bptr[BN / 32];
  #pragma unroll
  for (int b = 0; b < BN / 32; ++b) {
    int row = b * 32 + srow;
    bptr[b] = (const char*)(Be + (size_t)(n0 + row) * LDA + kbase)
              + ((slot ^ (row & 7)) * 16);
  }

  auto STAGE = [&](int buf, int t) {
    char* ab = (char*)&As[buf][0][0];
    #pragma unroll
    for (int b = 0; b < BM / 32; ++b)
      gload16(aptr[b] + t * 128, ab + b * 4096 + tid * 16);
    char* bb = (char*)&Bs[buf][0][0];
    #pragma unroll
    for (int b = 0; b < BN / 32; ++b)
      gload16(bptr[b] + t * 128, bb + b * 4096 + tid * 16);
  };

  f32x4 acc[MF][NF];
  #pragma unroll
  for (int m = 0; m < MF; ++m)
    #pragma unroll
    for (int n = 0; n < NF; ++n) acc[m][n] = 0.f;

  STAGE(0, 0);
  int cur = 0;
  for (int t = 0; t < KT; ++t) {
    __syncthreads();                 // drains stage of buf `cur`
    if (t + 1 < KT) STAGE(cur ^ 1, t + 1);   // in flight across MFMA
    #pragma unroll
    for (int ks = 0; ks < 2; ++ks) {
      bf16x8 af[MF], bv[NF];
      #pragma unroll
      for (int m = 0; m < MF; ++m) {
        int row = wm * (MF * 16) + m * 16 + lr;
        int sl = (ks * 4 + g) ^ (row & 7);
        af[m] = *(const bf16x8*)&As[cur][row][sl * 8];
      }
      #pragma unroll
      for (int n = 0; n < NF; ++n) {
        int row = wn * (NF * 16) + n * 16 + lr;
        int sl = (ks * 4 + g) ^ (row & 7);
        bv[n] = *(const bf16x8*)&Bs[cur][row][sl * 8];
      }
      #pragma unroll
      for (int m = 0; m < MF; ++m)
        #pragma unroll
        for (int n = 0; n < NF; ++n)
          acc[m][n] = __builtin_amdgcn_mfma_f32_16x16x32_bf16(af[m], bv[n], acc[m][n], 0, 0, 0);
    }
    cur ^= 1;
  }

  #pragma unroll
  for (int m = 0; m < MF; ++m) {
    #pragma unroll
    for (int q = 0; q < 4; ++q) {
      int rowl = wm * (MF * 16) + m * 16 + g * 4 + q;
      int row = row0 + rowl;
      bool valid = row < cnt;
      if constexpr (IS_L1) {
        #pragma unroll
        for (int n = 0; n < NF; ++n) {
          int col = n0 + wn * (NF * 16) + n * 16 + lr;
          int c = col >> 1;
          bool re = (col & 1) == 0;
          float v = acc[m][n][q] + (re ? bre[e * (NTOT / 2) + c] : bim[e * (NTOT / 2) + c]);
          float o = __shfl_xor(v, 1);
          float hr = re ? v : o, hi = re ? o : v;
          float amp = sqrtf(hr * hr + hi * hi + 1e-10f);
          float sc = fmaxf(amp + mb[e * (NTOT / 2) + c], 0.f) / (amp + 1e-10f);
          v *= sc;
          if (valid) OutBf[(size_t)(base + row) * NTOT + col] = (short)f2bf(v);
        }
      } else {
        if (valid) {
          float* Pr = OutP + ((size_t)s * TOKENS + base + row) * NTOT + n0;
          #pragma unroll
          for (int n = 0; n < NF; ++n)
            Pr[wn * (NF * 16) + n * 16 + lr] = acc[m][n][q];
        }
      }
    }
  }
}

// ---------------- split-K finalize: sum partials + bias, scatter ----------------
__global__ __launch_bounds__(256) void finalize_kernel(
    const float* __restrict__ P, const float* __restrict__ br2,
    const float* __restrict__ bi2, const int* __restrict__ perm,
    const int* __restrict__ rexp, float* __restrict__ out)
{
  int gid = blockIdx.x * 256 + threadIdx.x;   // 2048 * 256
  int i = gid >> 8;
  int n4 = (gid & 255) << 2;
  float4 v = *(const float4*)(P + (size_t)i * 1024 + n4);
  #pragma unroll
  for (int s = 1; s < 4; ++s) {
    float4 u = *(const float4*)(P + ((size_t)s * TOKENS + i) * 1024 + n4);
    v.x += u.x; v.y += u.y; v.z += u.z; v.w += u.w;
  }
  int e = rexp[i], tok = perm[i];
  int c0 = n4 >> 1;                 // cols n4..n4+3 = (re,im) of c0, c0+1
  float2 br = *(const float2*)(br2 + e * FDIM + c0);
  float2 bi = *(const float2*)(bi2 + e * FDIM + c0);
  float* outr = out;
  float* outi = out + (size_t)TOKENS * FDIM;
  outr[(size_t)tok * FDIM + c0]     = v.x + br.x;
  outi[(size_t)tok * FDIM + c0]     = v.y + bi.x;
  outr[(size_t)tok * FDIM + c0 + 1] = v.z + br.y;
  outi[(size_t)tok * FDIM + c0 + 1] = v.w + bi.y;
}

extern "C" void kernel_launch(void* const* d_in, const int* in_sizes, int n_in,
                              void* d_out, int out_size, void* d_ws, size_t ws_size,
                              hipStream_t stream)
{
  const float* xr  = (const float*)d_in[0];
  const float* xi  = (const float*)d_in[1];
  const float* Wr1 = (const float*)d_in[2];
  const float* Wi1 = (const float*)d_in[3];
  const float* br1 = (const float*)d_in[4];
  const float* bi1 = (const float*)d_in[5];
  const float* mb  = (const float*)d_in[6];
  const float* Wr2 = (const float*)d_in[7];
  const float* Wi2 = (const float*)d_in[8];
  const float* br2 = (const float*)d_in[9];
  const float* bi2 = (const float*)d_in[10];
  float* out = (float*)d_out;

  char* ws = (char*)d_ws;
  int* counts = (int*)(ws + 0);
  int* offs   = (int*)(ws + 64);
  int* idx    = (int*)(ws + 128);
  int* perm   = (int*)(ws + 8320);
  int* rexp   = (int*)(ws + 16512);

  const size_t A1_OFF = 32768;
  const size_t A2_OFF = A1_OFF + (size_t)TOKENS * 1024 * 2;          // +4 MB
  const size_t B1_OFF = A2_OFF + (size_t)TOKENS * 4096 * 2;          // +16 MB
  const size_t B2_OFF = B1_OFF + (size_t)NEXP * 4096 * 1024 * 2;     // +64 MB

  short* A1 = (short*)(ws + A1_OFF);
  short* A2 = (short*)(ws + A2_OFF);
  short* B1 = (short*)(ws + B1_OFF);
  short* B2 = (short*)(ws + B2_OFF);
  float* P  = (float*)(ws + B1_OFF);   // reuse B1 region (L1-only), 32 MB of 64

  hipMemsetAsync(counts, 0, 64, stream);
  route_kernel<<<TOKENS, 256, 0, stream>>>(xr, xi, idx, counts);
  scatter_kernel<<<1, 256, 0, stream>>>(idx, counts, offs, perm, rexp);

  pack_x_kernel<<<TOKENS * 128 / 256, 256, 0, stream>>>(xr, xi, perm, A1);
  pack_w_kernel<512, 2048><<<dim3(2048 / 32, 512 / 32, NEXP), 256, 0, stream>>>(
      Wr1, Wi1, (unsigned int*)B1);
  pack_w_kernel<2048, 512><<<dim3(512 / 32, 2048 / 32, NEXP), 256, 0, stream>>>(
      Wr2, Wi2, (unsigned int*)B2);

  // layer1: [2048 x 1024] @ B1[4096][1024] -> A2 bf16 (bias+ModReLU fused)
  gemm_mfma2<128, 4, 4, 1024, 4096, true>
      <<<dim3(4096 / 128, TOKENS / 128, NEXP), 256, 0, stream>>>(
      A1, B1, counts, offs, br1, bi1, mb, A2, nullptr);
  // layer2: [2048 x 4096] @ B2[1024][4096], split-K=4 -> P partials
  gemm_mfma2<64, 2, 4, 4096, 1024, false>
      <<<dim3(1024 / 128, TOKENS / 64, NEXP * 4), 256, 0, stream>>>(
      A2, B2, counts, offs, nullptr, nullptr, nullptr, nullptr, P);
  finalize_kernel<<<TOKENS * 256 / 256, 256, 0, stream>>>(
      P, br2, bi2, perm, rexp, out);
}

// Round 5
// 145.420 us; speedup vs baseline: 8.1268x; 1.3712x over previous
//
#include <hip/hip_runtime.h>
#include <hip/hip_bf16.h>

#define TOKENS 2048
#define FDIM 512
#define HDIM 2048
#define NEXP 8
#define PI_F 3.14159265358979323846f

typedef __attribute__((ext_vector_type(8))) short bf16x8;
typedef __attribute__((ext_vector_type(4))) float f32x4;

__device__ __forceinline__ unsigned short f2bf(float f) {
  unsigned int u = __float_as_uint(f);
  unsigned int r = (u + 0x7fffu + ((u >> 16) & 1u)) >> 16;
  return (unsigned short)r;
}

__device__ __forceinline__ void gload16(const void* g, void* l) {
  __builtin_amdgcn_global_load_lds(
      (const __attribute__((address_space(1))) unsigned int*)g,
      (__attribute__((address_space(3))) unsigned int*)l, 16, 0, 0);
}

// ---------------- routing ----------------
__global__ __launch_bounds__(256) void route_kernel(
    const float* __restrict__ xr, const float* __restrict__ xi,
    int* __restrict__ idx, int* __restrict__ counts)
{
  int t = blockIdx.x;
  const float* r  = xr + (size_t)t * FDIM;
  const float* im = xi + (size_t)t * FDIM;
  int tid = threadIdx.x;
  float sc = 0.f, ss = 0.f;
  for (int f = tid; f < FDIM; f += 256) {
    float a = r[f], b = im[f];
    float h2 = a * a + b * b;
    if (h2 > 0.f) {
      float h = sqrtf(h2);
      sc += a / h;
      ss += b / h;
    } else {
      sc += 1.f;
    }
  }
  #pragma unroll
  for (int off = 32; off > 0; off >>= 1) {
    sc += __shfl_down(sc, off);
    ss += __shfl_down(ss, off);
  }
  __shared__ float red[8];
  int wave = tid >> 6;
  if ((tid & 63) == 0) { red[wave * 2] = sc; red[wave * 2 + 1] = ss; }
  __syncthreads();
  if (tid == 0) {
    float c = red[0] + red[2] + red[4] + red[6];
    float s = red[1] + red[3] + red[5] + red[7];
    float phase = atan2f(s, c);
    float norm = (phase + PI_F) / (2.f * PI_F);
    int e = (int)floorf(norm * (float)NEXP);
    e = min(max(e, 0), NEXP - 1);
    idx[t] = e;
    atomicAdd(&counts[e], 1);
  }
}

// deterministic scatter: perm within each expert is in ascending token order
__global__ __launch_bounds__(256) void scatter_kernel(
    const int* __restrict__ idx, const int* __restrict__ counts,
    int* __restrict__ offs, int* __restrict__ perm, int* __restrict__ rexp)
{
  __shared__ int base_e[NEXP];
  __shared__ int tcnt[256][NEXP];
  int tid = threadIdx.x;
  if (tid == 0) {
    int acc = 0;
    for (int e = 0; e < NEXP; ++e) { base_e[e] = acc; offs[e] = acc; acc += counts[e]; }
  }
  int t0 = tid * 8;
  int eo[8];
  int loc[NEXP];
  #pragma unroll
  for (int e = 0; e < NEXP; ++e) loc[e] = 0;
  #pragma unroll
  for (int j = 0; j < 8; ++j) { eo[j] = idx[t0 + j]; loc[eo[j]]++; }
  #pragma unroll
  for (int e = 0; e < NEXP; ++e) tcnt[tid][e] = loc[e];
  __syncthreads();
  if (tid < NEXP) {
    int e = tid, run = 0;
    for (int i = 0; i < 256; ++i) { int v = tcnt[i][e]; tcnt[i][e] = run; run += v; }
  }
  __syncthreads();
  #pragma unroll
  for (int e = 0; e < NEXP; ++e) loc[e] = base_e[e] + tcnt[tid][e];
  #pragma unroll
  for (int j = 0; j < 8; ++j) {
    int e = eo[j];
    int pos = loc[e]++;
    perm[pos] = t0 + j;
    rexp[pos] = e;
  }
}

// ---------------- packing ----------------
__global__ __launch_bounds__(256) void pack_x_kernel(
    const float* __restrict__ xr, const float* __restrict__ xi,
    const int* __restrict__ perm,
    short* __restrict__ Ar, short* __restrict__ Ai)
{
  int gid = blockIdx.x * 256 + threadIdx.x;   // 2048 * 128
  int i = gid >> 7;
  int c4 = (gid & 127) * 4;
  int tok = perm[i];
  float4 r = *(const float4*)(xr + (size_t)tok * FDIM + c4);
  float4 m = *(const float4*)(xi + (size_t)tok * FDIM + c4);
  unsigned short orr[4] = { f2bf(r.x), f2bf(r.y), f2bf(r.z), f2bf(r.w) };
  unsigned short oii[4] = { f2bf(m.x), f2bf(m.y), f2bf(m.z), f2bf(m.w) };
  *(int2*)(Ar + (size_t)i * FDIM + c4) = *(const int2*)orr;
  *(int2*)(Ai + (size_t)i * FDIM + c4) = *(const int2*)oii;
}

// W[e][K][N] fp32 (r,i) -> Wp[e][2][N][K] bf16 (plane 0 = Wr^T, 1 = Wi^T)
template<int K, int N>
__global__ __launch_bounds__(256) void pack_w_kernel(
    const float* __restrict__ Wr, const float* __restrict__ Wi,
    short* __restrict__ Wp)
{
  int e = blockIdx.z;
  int k0 = blockIdx.y * 32, n0 = blockIdx.x * 32;
  __shared__ float tr[32][33], ti[32][33];
  int tid = threadIdx.x;
  int row = tid >> 3, c4 = (tid & 7) * 4;
  const float* wr = Wr + ((size_t)e * K + k0) * N + n0;
  const float* wi = Wi + ((size_t)e * K + k0) * N + n0;
  float4 vr = *(const float4*)(wr + (size_t)row * N + c4);
  float4 vi = *(const float4*)(wi + (size_t)row * N + c4);
  *(float4*)&tr[row][c4] = vr;
  *(float4*)&ti[row][c4] = vi;
  __syncthreads();
  int nl = tid >> 3, k4 = (tid & 7) * 4;
  unsigned short pr[4], pi[4];
  #pragma unroll
  for (int j = 0; j < 4; ++j) {
    pr[j] = f2bf(tr[k4 + j][nl]);
    pi[j] = f2bf(ti[k4 + j][nl]);
  }
  size_t b0 = (((size_t)e * 2 + 0) * N + n0 + nl) * K + k0 + k4;
  size_t b1 = (((size_t)e * 2 + 1) * N + n0 + nl) * K + k0 + k4;
  *(int2*)(Wp + b0) = *(const int2*)pr;
  *(int2*)(Wp + b1) = *(const int2*)pi;
}

// ---------------- plane-separated complex MFMA grouped GEMM ----------------
// Conservative 2-barrier-per-step dbuf (replay-safety; see r4 post-mortem).
template<int LDK, int NC, bool IS_L1>
__global__ __launch_bounds__(256) void gemm_cplx(
    const short* __restrict__ Apr, const short* __restrict__ Api,
    const short* __restrict__ Wp,
    const int* __restrict__ counts, const int* __restrict__ offs,
    const float* __restrict__ bre, const float* __restrict__ bim,
    const float* __restrict__ mb,
    short* __restrict__ Or, short* __restrict__ Oi, float* __restrict__ P)
{
  constexpr int NX = NC / 64;
  constexpr int KT = 16;     // 16 steps x BK=32 = 512 K-chunk
  int bid = blockIdx.x;
  int virt = (bid & 7) * 256 + (bid >> 3);   // XCD-chunked: one expert per XCD
  int e = virt >> 8, rem = virt & 255;
  int x = rem % NX;
  int q = rem / NX;
  int y = q & 7, s = q >> 3;                 // IS_L1: s=0
  int cnt = counts[e];
  int row0 = y * 64;
  if (row0 >= cnt) return;
  int base = offs[e];
  int n0c = x * 64;
  int kbase = s * 512;

  __shared__ __align__(16) short L[2][4][64][32];   // [buf][Ar,Ai,Wr,Wi][row][k]

  int tid = threadIdx.x;
  int lane = tid & 63;
  int w = tid >> 6, wm = w >> 1, wn = w & 1;
  int lr = lane & 15, g = lane >> 4;
  int ssw = g ^ ((lr >> 1) & 3);     // swizzled 16B slot for fragment reads

  int srow = tid >> 2, slot = tid & 3;
  int scol = (slot ^ ((srow >> 1) & 3)) * 16;   // pre-swizzled source byte offset
  int arow = min(row0 + srow, cnt - 1);
  const char* pAr = (const char*)(Apr + (size_t)(base + arow) * LDK + kbase) + scol;
  const char* pAi = (const char*)(Api + (size_t)(base + arow) * LDK + kbase) + scol;
  const short* We = Wp + (size_t)e * 2 * NC * LDK;
  const char* pWr = (const char*)(We + (size_t)(n0c + srow) * LDK + kbase) + scol;
  const char* pWi = (const char*)(We + ((size_t)NC + n0c + srow) * LDK + kbase) + scol;

  auto STAGE = [&](int buf, int t) {
    char* d = (char*)&L[buf][0][0][0] + tid * 16;
    gload16(pAr + t * 64, d);
    gload16(pAi + t * 64, d + 4096);
    gload16(pWr + t * 64, d + 8192);
    gload16(pWi + t * 64, d + 12288);
  };

  f32x4 accr[2][2], acci[2][2];
  #pragma unroll
  for (int m = 0; m < 2; ++m)
    #pragma unroll
    for (int n = 0; n < 2; ++n) { accr[m][n] = 0.f; acci[m][n] = 0.f; }

  const bf16x8 SGN = {(short)0x8000, (short)0x8000, (short)0x8000, (short)0x8000,
                      (short)0x8000, (short)0x8000, (short)0x8000, (short)0x8000};

  auto COMPUTE = [&](int buf) {
    const short* Lb = &L[buf][0][0][0];
    bf16x8 ar[2], ai[2], an[2], wr[2], wi[2];
    #pragma unroll
    for (int m = 0; m < 2; ++m) {
      int off = (wm * 32 + m * 16 + lr) * 32 + ssw * 8;
      ar[m] = *(const bf16x8*)(Lb + off);
      ai[m] = *(const bf16x8*)(Lb + 2048 + off);
      an[m] = ai[m] ^ SGN;
    }
    #pragma unroll
    for (int n = 0; n < 2; ++n) {
      int off = (wn * 32 + n * 16 + lr) * 32 + ssw * 8;
      wr[n] = *(const bf16x8*)(Lb + 4096 + off);
      wi[n] = *(const bf16x8*)(Lb + 6144 + off);
    }
    #pragma unroll
    for (int m = 0; m < 2; ++m)
      #pragma unroll
      for (int n = 0; n < 2; ++n) {
        accr[m][n] = __builtin_amdgcn_mfma_f32_16x16x32_bf16(ar[m], wr[n], accr[m][n], 0, 0, 0);
        accr[m][n] = __builtin_amdgcn_mfma_f32_16x16x32_bf16(an[m], wi[n], accr[m][n], 0, 0, 0);
        acci[m][n] = __builtin_amdgcn_mfma_f32_16x16x32_bf16(ar[m], wi[n], acci[m][n], 0, 0, 0);
        acci[m][n] = __builtin_amdgcn_mfma_f32_16x16x32_bf16(ai[m], wr[n], acci[m][n], 0, 0, 0);
      }
  };

  STAGE(0, 0);
  int cur = 0;
  for (int t = 0; t < KT; ++t) {
    __syncthreads();                          // stage(cur,t) drained (all waves)
    if (t + 1 < KT) STAGE(cur ^ 1, t + 1);    // prefetch next buffer
    COMPUTE(cur);
    __syncthreads();                          // all reads of cur complete
    cur ^= 1;
  }

  // epilogue
  #pragma unroll
  for (int m = 0; m < 2; ++m) {
    #pragma unroll
    for (int qq = 0; qq < 4; ++qq) {
      int row = row0 + wm * 32 + m * 16 + g * 4 + qq;
      if (row >= cnt) continue;
      #pragma unroll
      for (int n = 0; n < 2; ++n) {
        int c = n0c + wn * 32 + n * 16 + lr;
        if constexpr (IS_L1) {
          float hr = accr[m][n][qq] + bre[e * NC + c];
          float hi = acci[m][n][qq] + bim[e * NC + c];
          float s2 = hr * hr + hi * hi + 1e-10f;
          float rr = __frsqrt_rn(s2);
          float amp = s2 * rr;
          float scl = fmaxf(amp + mb[e * NC + c], 0.f) * rr;
          Or[(size_t)(base + row) * NC + c] = (short)f2bf(hr * scl);
          Oi[(size_t)(base + row) * NC + c] = (short)f2bf(hi * scl);
        } else {
          float* Pr = P + ((size_t)s * TOKENS + base + row) * 1024;
          Pr[c] = accr[m][n][qq];
          Pr[512 + c] = acci[m][n][qq];
        }
      }
    }
  }
}

// ---------------- split-K finalize ----------------
__global__ __launch_bounds__(256) void finalize_kernel(
    const float* __restrict__ P, const float* __restrict__ br2,
    const float* __restrict__ bi2, const int* __restrict__ perm,
    const int* __restrict__ rexp, float* __restrict__ out)
{
  int gid = blockIdx.x * 256 + threadIdx.x;   // 2048 * 128
  int i = gid >> 7;
  int c4 = (gid & 127) * 4;
  float4 vr = *(const float4*)(P + (size_t)i * 1024 + c4);
  float4 vi = *(const float4*)(P + (size_t)i * 1024 + 512 + c4);
  #pragma unroll
  for (int s = 1; s < 4; ++s) {
    float4 ur = *(const float4*)(P + ((size_t)s * TOKENS + i) * 1024 + c4);
    float4 ui = *(const float4*)(P + ((size_t)s * TOKENS + i) * 1024 + 512 + c4);
    vr.x += ur.x; vr.y += ur.y; vr.z += ur.z; vr.w += ur.w;
    vi.x += ui.x; vi.y += ui.y; vi.z += ui.z; vi.w += ui.w;
  }
  int e = rexp[i], tok = perm[i];
  float4 br = *(const float4*)(br2 + e * FDIM + c4);
  float4 bi = *(const float4*)(bi2 + e * FDIM + c4);
  vr.x += br.x; vr.y += br.y; vr.z += br.z; vr.w += br.w;
  vi.x += bi.x; vi.y += bi.y; vi.z += bi.z; vi.w += bi.w;
  *(float4*)(out + (size_t)tok * FDIM + c4) = vr;
  *(float4*)(out + (size_t)TOKENS * FDIM + (size_t)tok * FDIM + c4) = vi;
}

extern "C" void kernel_launch(void* const* d_in, const int* in_sizes, int n_in,
                              void* d_out, int out_size, void* d_ws, size_t ws_size,
                              hipStream_t stream)
{
  const float* xr  = (const float*)d_in[0];
  const float* xi  = (const float*)d_in[1];
  const float* Wr1 = (const float*)d_in[2];
  const float* Wi1 = (const float*)d_in[3];
  const float* br1 = (const float*)d_in[4];
  const float* bi1 = (const float*)d_in[5];
  const float* mb  = (const float*)d_in[6];
  const float* Wr2 = (const float*)d_in[7];
  const float* Wi2 = (const float*)d_in[8];
  const float* br2 = (const float*)d_in[9];
  const float* bi2 = (const float*)d_in[10];
  float* out = (float*)d_out;

  char* ws = (char*)d_ws;
  int* counts = (int*)(ws + 0);
  int* offs   = (int*)(ws + 64);
  int* idx    = (int*)(ws + 128);
  int* perm   = (int*)(ws + 8320);
  int* rexp   = (int*)(ws + 16512);

  size_t off = 32768;
  short* A1r = (short*)(ws + off); off += (size_t)TOKENS * FDIM * 2;
  short* A1i = (short*)(ws + off); off += (size_t)TOKENS * FDIM * 2;
  short* A2r = (short*)(ws + off); off += (size_t)TOKENS * HDIM * 2;
  short* A2i = (short*)(ws + off); off += (size_t)TOKENS * HDIM * 2;
  short* W1p = (short*)(ws + off); off += (size_t)NEXP * 2 * HDIM * FDIM * 2;
  short* W2p = (short*)(ws + off); off += (size_t)NEXP * 2 * FDIM * HDIM * 2;
  float* P   = (float*)(ws + off);

  hipMemsetAsync(counts, 0, 64, stream);
  route_kernel<<<TOKENS, 256, 0, stream>>>(xr, xi, idx, counts);
  scatter_kernel<<<1, 256, 0, stream>>>(idx, counts, offs, perm, rexp);

  pack_x_kernel<<<TOKENS * 128 / 256, 256, 0, stream>>>(xr, xi, perm, A1r, A1i);
  pack_w_kernel<FDIM, HDIM><<<dim3(HDIM / 32, FDIM / 32, NEXP), 256, 0, stream>>>(
      Wr1, Wi1, W1p);
  pack_w_kernel<HDIM, FDIM><<<dim3(FDIM / 32, HDIM / 32, NEXP), 256, 0, stream>>>(
      Wr2, Wi2, W2p);

  gemm_cplx<FDIM, HDIM, true><<<2048, 256, 0, stream>>>(
      A1r, A1i, W1p, counts, offs, br1, bi1, mb, A2r, A2i, nullptr);
  gemm_cplx<HDIM, FDIM, false><<<2048, 256, 0, stream>>>(
      A2r, A2i, W2p, counts, offs, nullptr, nullptr, nullptr, nullptr, nullptr, P);

  finalize_kernel<<<TOKENS * 128 / 256, 256, 0, stream>>>(
      P, br2, bi2, perm, rexp, out);
}